// Round 9
// baseline (120.758 us; speedup 1.0000x reference)
//
#include <hip/hip_runtime.h>
#include <math.h>
#include <type_traits>

#define D_MODEL 1024
#define N_HEADS 16
#define D_KK    64
#define B_SZ    2
#define SEQ     2048
#define M_TOTAL (B_SZ * SEQ)   // 4096

// 0.125 * log2(e): folds attention scale AND exp->exp2 conversion into Q
#define QSCALE 0.18033688011112042f
// fixed softmax "max" in exp2 domain (|S| <~ 8 for N(0,1.44) scores; softmax
// is shift-invariant and bf16 P is exponent-invariant -> no max-reduce needed)
#define FIXM 12.0f

typedef __attribute__((ext_vector_type(8)))  short short8;
typedef __attribute__((ext_vector_type(4)))  float f32x4;
typedef __attribute__((ext_vector_type(16))) float f32x16;

static __device__ __forceinline__ ushort f2bf(float f) {
    union { float f; unsigned u; } c; c.f = f;
    unsigned u = c.u;
    unsigned r = (u + 0x7fffu + ((u >> 16) & 1u)) >> 16;   // RNE
    return (ushort)r;
}

// v_cvt_pk_bf16_f32: dst = [bf16(b) : bf16(a)]
static __device__ __forceinline__ unsigned cvtpk(float a, float b) {
    unsigned r;
    asm("v_cvt_pk_bf16_f32 %0, %1, %2" : "=v"(r) : "v"(a), "v"(b));
    return r;
}
// v_permlane32_swap_b32: a.hi32lanes <-> b.lo32lanes
static __device__ __forceinline__ void pswap(unsigned &a, unsigned &b) {
    asm("v_permlane32_swap_b32 %0, %1" : "+v"(a), "+v"(b));
}

static __device__ __forceinline__ void gload16(const void* g, void* l) {
    __builtin_amdgcn_global_load_lds(
        (const __attribute__((address_space(1))) void*)g,
        (__attribute__((address_space(3))) void*)l, 16, 0, 0);
}

// ---------------------------------------------------------------------------
// fp32 -> bf16 conversion: x and the four weight matrices.
// ---------------------------------------------------------------------------
__global__ __launch_bounds__(256)
void cvt_kernel(const float* __restrict__ x,  const float* __restrict__ wq,
                const float* __restrict__ wk, const float* __restrict__ wv,
                const float* __restrict__ wo,
                ushort* __restrict__ xb,  ushort* __restrict__ wqb,
                ushort* __restrict__ wkb, ushort* __restrict__ wvb,
                ushort* __restrict__ wob)
{
    const float* s; ushort* d; int n4;
    switch (blockIdx.y) {
        case 0:  s = x;  d = xb;  n4 = M_TOTAL * D_MODEL / 4; break;
        case 1:  s = wq; d = wqb; n4 = D_MODEL * D_MODEL / 4; break;
        case 2:  s = wk; d = wkb; n4 = D_MODEL * D_MODEL / 4; break;
        case 3:  s = wv; d = wvb; n4 = D_MODEL * D_MODEL / 4; break;
        default: s = wo; d = wob; n4 = D_MODEL * D_MODEL / 4; break;
    }
    const int stride = gridDim.x * blockDim.x;
    for (int i = blockIdx.x * blockDim.x + threadIdx.x; i < n4; i += stride) {
        float4 v = reinterpret_cast<const float4*>(s)[i];
        ushort4 u;
        u.x = f2bf(v.x); u.y = f2bf(v.y); u.z = f2bf(v.z); u.w = f2bf(v.w);
        reinterpret_cast<ushort4*>(d)[i] = u;
    }
}

// ---------------------------------------------------------------------------
// bf16 MFMA GEMM v2 (unchanged): BM=128 BN=64 BK=64, dbuf prefetch,
// pre-swizzled global_load_lds, XCD-chunked flat decode.
// ---------------------------------------------------------------------------
template<int EPI>
__global__ __launch_bounds__(256)
void gemm_mfma(const ushort* __restrict__ A,
               const ushort* __restrict__ W0, const float* __restrict__ b0, void* __restrict__ C0,
               const ushort* __restrict__ W1, const float* __restrict__ b1, void* __restrict__ C1,
               const ushort* __restrict__ W2, const float* __restrict__ b2, void* __restrict__ C2)
{
    constexpr int K = D_MODEL;

    __shared__ ushort As[2][128 * 64];   // 32 KB
    __shared__ ushort Bs[2][64 * 64];    // 16 KB

    const int id  = blockIdx.x;
    const int xcd = id & 7;
    const int j   = id >> 3;
    const int mt  = xcd * 4 + (j & 3);
    const int ntz = j >> 2;
    const int nt  = ntz & 15;
    const int z   = ntz >> 4;

    const ushort* W    = W0;
    const float*  bias = b0;
    void*         C    = C0;
    if (z == 1) { W = W1; bias = b1; C = C1; }
    else if (z == 2) { W = W2; bias = b2; C = C2; }

    const int m0 = mt * 128;
    const int n0 = nt * 64;

    const int tid  = threadIdx.x;
    const int w    = tid >> 6;
    const int lane = tid & 63;
    const int lr   = lane & 15;
    const int lc   = lane >> 4;
    const int wr   = w >> 1;
    const int wc   = w & 1;

    const int rsub = lane >> 3;
    const int csw  = ((lane & 7) ^ rsub) << 3;

    const ushort* gA = A + (size_t)(m0 + w * 8 + rsub) * K + csw;
    const ushort* gB = W + (size_t)(n0 + w * 8 + rsub) * K + csw;

    f32x4 acc[4][2];
#pragma unroll
    for (int m = 0; m < 4; ++m)
#pragma unroll
        for (int n = 0; n < 2; ++n) acc[m][n] = (f32x4)0.0f;

#pragma unroll
    for (int ca = 0; ca < 4; ++ca)
        gload16(gA + (size_t)(32 * ca) * K, &As[0][(w + 4 * ca) * 512]);
#pragma unroll
    for (int cb = 0; cb < 2; ++cb)
        gload16(gB + (size_t)(32 * cb) * K, &Bs[0][(w + 4 * cb) * 512]);
    __syncthreads();

    const int swz = (lr & 7) << 4;
    int buf = 0;
    for (int it = 0; it < 16; ++it) {
        if (it < 15) {
            const int kn = (it + 1) * 64;
#pragma unroll
            for (int ca = 0; ca < 4; ++ca)
                gload16(gA + (size_t)(32 * ca) * K + kn, &As[buf ^ 1][(w + 4 * ca) * 512]);
#pragma unroll
            for (int cb = 0; cb < 2; ++cb)
                gload16(gB + (size_t)(32 * cb) * K + kn, &Bs[buf ^ 1][(w + 4 * cb) * 512]);
        }

        short8 af[4][2], bfr[2][2];
#pragma unroll
        for (int m = 0; m < 4; ++m) {
            const int rbyte = (wr * 64 + m * 16 + lr) * 128;
#pragma unroll
            for (int kk = 0; kk < 2; ++kk)
                af[m][kk] = *reinterpret_cast<const short8*>(
                    &As[buf][(rbyte + ((kk * 64 + lc * 16) ^ swz)) >> 1]);
        }
#pragma unroll
        for (int n = 0; n < 2; ++n) {
            const int rbyte = (wc * 32 + n * 16 + lr) * 128;
#pragma unroll
            for (int kk = 0; kk < 2; ++kk)
                bfr[n][kk] = *reinterpret_cast<const short8*>(
                    &Bs[buf][(rbyte + ((kk * 64 + lc * 16) ^ swz)) >> 1]);
        }
#pragma unroll
        for (int kk = 0; kk < 2; ++kk)
#pragma unroll
            for (int m = 0; m < 4; ++m)
#pragma unroll
                for (int n = 0; n < 2; ++n)
                    acc[m][n] = __builtin_amdgcn_mfma_f32_16x16x32_bf16(
                        af[m][kk], bfr[n][kk], acc[m][n], 0, 0, 0);

        __syncthreads();
        buf ^= 1;
    }

    float bv[2];
#pragma unroll
    for (int n = 0; n < 2; ++n) bv[n] = bias[n0 + wc * 32 + n * 16 + lr];
    const int row_base = m0 + wr * 64;

    if (EPI == 0) {
        float* Cf = (float*)C;
#pragma unroll
        for (int m = 0; m < 4; ++m)
#pragma unroll
        for (int r = 0; r < 4; ++r) {
            const int row = row_base + m * 16 + lc * 4 + r;
#pragma unroll
            for (int n = 0; n < 2; ++n)
                Cf[(size_t)row * D_MODEL + n0 + wc * 32 + n * 16 + lr] =
                    acc[m][n][r] + bv[n];
        }
    } else {
        ushort* Cu = (ushort*)C;
        const bool vt   = (z == 2);
        const float osc = (z == 0) ? QSCALE : 1.0f;
#pragma unroll
        for (int m = 0; m < 4; ++m) {
            const int row4 = row_base + m * 16 + lc * 4;
            const int bb = row4 >> 11;
            const int ss = row4 & 2047;
            const size_t bhbase = (size_t)bb * N_HEADS;
#pragma unroll
            for (int n = 0; n < 2; ++n) {
                const int col = n0 + wc * 32 + n * 16 + lr;
                const int h = col >> 6, d = col & 63;
                if (vt) {
                    ushort4 u;
                    u.x = f2bf(acc[m][n][0] + bv[n]);
                    u.y = f2bf(acc[m][n][1] + bv[n]);
                    u.z = f2bf(acc[m][n][2] + bv[n]);
                    u.w = f2bf(acc[m][n][3] + bv[n]);
                    *reinterpret_cast<ushort4*>(
                        &Cu[((bhbase + h) * D_KK + d) * SEQ + ss]) = u;
                } else {
#pragma unroll
                    for (int r = 0; r < 4; ++r)
                        Cu[((bhbase + h) * SEQ + ss + r) * D_KK + d] =
                            f2bf((acc[m][n][r] + bv[n]) * osc);
                }
            }
        }
    }
}

// ---------------------------------------------------------------------------
// MFMA flash attention v6: 32x32x16 MFMA, 32 q-rows/wave, P entirely
// in-register (cvt_pk + permlane32_swap), fixed-max exp2 softmax.
// Per wave-tile LDS: 8 K-reads + 8 V-reads (b128) only.
// Block = 2 waves (64 q rows); 512 blocks = 32 bh x 16 pairs {qx, 31-qx}.
// Q,K: [bh][s][64] bf16 (Q pre-scaled).  Vt: [bh][64][s] bf16.
// Out: [b][s][h*64+d] bf16.
// ---------------------------------------------------------------------------
__global__ __launch_bounds__(128)
void attn_mfma_kernel(const ushort* __restrict__ Qb, const ushort* __restrict__ Kb,
                      const ushort* __restrict__ Vt, ushort* __restrict__ Ob)
{
    __shared__ ushort Ks[2][4096];      // [64 k][128 B], XOR-swizzled rows
    __shared__ ushort Vs[2][4096];      // [64 d][128 B] (V^T), XOR-swizzled

    const int tid  = threadIdx.x;
    const int w    = tid >> 6;           // 0..1
    const int lane = tid & 63;
    const int l31  = lane & 31;
    const int hi   = lane >> 5;          // 0..1
    const int swl  = (lane & 7) << 4;    // frag-read XOR (bytes)

    // 512 = 8 xcd * 4 bh * 16 q-pairs
    const int id  = blockIdx.x;
    const int xcd = id & 7;
    const int j   = id >> 3;             // 0..63
    const int bh  = xcd * 4 + (j & 3);
    const int qx  = j >> 2;              // 0..15
    const int b   = bh >> 4;
    const int h   = bh & 15;

    const ushort* Kbase = Kb + (size_t)bh * SEQ * D_KK;
    const ushort* Vbase = Vt + (size_t)bh * D_KK * SEQ;

    // staging: 8 chunks of 1KB per matrix; wave w does chunks {w,w+2,w+4,w+6}
    const int rsub = lane >> 3;
    const int csw  = ((lane & 7) ^ rsub) << 3;

    auto stage = [&](int kofs, int s) {
#pragma unroll
        for (int cc = 0; cc < 4; ++cc) {
            const int c = w + cc * 2;
            gload16(Kbase + (size_t)(kofs + c * 8 + rsub) * D_KK + csw,
                    &Ks[s][c * 512]);
            gload16(Vbase + (size_t)(c * 8 + rsub) * SEQ + kofs + csw,
                    &Vs[s][c * 512]);
        }
    };

    // build PV B-frag from 8 packed f32 p-values (k32 = o..o+7 own/partner mix)
    auto makefrag = [&](const f32x16& sv, int o) -> short8 {
        unsigned u0 = cvtpk(sv[o + 0], sv[o + 1]);
        unsigned u1 = cvtpk(sv[o + 2], sv[o + 3]);
        unsigned u2 = cvtpk(sv[o + 4], sv[o + 5]);
        unsigned u3 = cvtpk(sv[o + 6], sv[o + 7]);
        pswap(u0, u2);
        pswap(u1, u3);
        int4 t = make_int4((int)u0, (int)u1, (int)u2, (int)u3);
        return *reinterpret_cast<short8*>(&t);
    };

    const int qrel = 32 * w + l31;       // q offset within 64-row block

    for (int half = 0; half < 2; ++half) {
        const int qb  = half ? (31 - qx) : qx;
        const int q0  = qb * 64;
        const int qw0 = q0 + w * 32;
        const int nt  = qb + 1;

        // Q B-frags: col q = l31, d = 16*ds + 8*hi + j  (held all half)
        const ushort* Qp = Qb + ((size_t)bh * SEQ + qw0 + l31) * D_KK + 8 * hi;
        short8 qf[4];
#pragma unroll
        for (int ds = 0; ds < 4; ++ds)
            qf[ds] = *reinterpret_cast<const short8*>(Qp + 16 * ds);

        f32x16 ot0 = (f32x16)0.0f, ot1 = (f32x16)0.0f;
        float l_run = 0.0f;

        stage(0, 0);
        __syncthreads();

        auto tile_body = [&](int buf, auto maskc) {
            constexpr bool MASK = decltype(maskc)::value;
            const ushort* Ksb = &Ks[buf][0];
            const ushort* Vsb = &Vs[buf][0];

            // ---- S^T(64k x 32q) = K . Q^T : 8 MFMA, 8 K-reads ----
            f32x16 s0 = (f32x16)0.0f, s1 = (f32x16)0.0f;
#pragma unroll
            for (int ds = 0; ds < 4; ++ds) {
                const int cb = (32 * ds + 16 * hi) ^ swl;
                const short8 a0 = *reinterpret_cast<const short8*>(
                    &Ksb[(l31 * 128 + cb) >> 1]);
                const short8 a1 = *reinterpret_cast<const short8*>(
                    &Ksb[((32 + l31) * 128 + cb) >> 1]);
                s0 = __builtin_amdgcn_mfma_f32_32x32x16_bf16(a0, qf[ds], s0, 0, 0, 0);
                s1 = __builtin_amdgcn_mfma_f32_32x32x16_bf16(a1, qf[ds], s1, 0, 0, 0);
            }

            // ---- causal mask (diagonal tile only) ----
            if (MASK) {
#pragma unroll
                for (int reg = 0; reg < 16; ++reg) {
                    const int k32 = (reg & 3) + 8 * (reg >> 2) + 4 * hi;
                    if (k32 > qrel)      s0[reg] = -1e30f;
                    if (k32 + 32 > qrel) s1[reg] = -1e30f;
                }
            }

            // ---- p = exp2(s - FIXM); lane-local row sum ----
            float rsum = 0.0f;
#pragma unroll
            for (int reg = 0; reg < 16; ++reg) {
                const float p0 = __builtin_amdgcn_exp2f(s0[reg] - FIXM);
                const float p1 = __builtin_amdgcn_exp2f(s1[reg] - FIXM);
                s0[reg] = p0; s1[reg] = p1;
                rsum += p0 + p1;
            }
            l_run += rsum;

            // ---- P -> B-frags in-register (cvt_pk + permlane32_swap) ----
            const short8 pb0 = makefrag(s0, 0);
            const short8 pb1 = makefrag(s0, 8);
            const short8 pb2 = makefrag(s1, 0);
            const short8 pb3 = makefrag(s1, 8);

            // ---- O^T(64d x 32q) += V^T . P^T : 8 MFMA, 8 V-reads ----
#pragma unroll
            for (int dg = 0; dg < 2; ++dg) {
                const int row = dg * 32 + l31;
                f32x16& ot = dg ? ot1 : ot0;
#pragma unroll
                for (int ks = 0; ks < 4; ++ks) {
                    const int cb = (32 * ks + 16 * hi) ^ swl;
                    const short8 vf = *reinterpret_cast<const short8*>(
                        &Vsb[(row * 128 + cb) >> 1]);
                    const short8 pb = (ks == 0) ? pb0 : (ks == 1) ? pb1
                                     : (ks == 2) ? pb2 : pb3;
                    ot = __builtin_amdgcn_mfma_f32_32x32x16_bf16(vf, pb, ot, 0, 0, 0);
                }
            }
        };

        int buf = 0;
        for (int it = 0; it < nt; ++it) {
            if (it + 1 < nt) stage((it + 1) * 64, buf ^ 1);
            if (it == nt - 1)
                tile_body(buf, std::integral_constant<bool, true>{});
            else
                tile_body(buf, std::integral_constant<bool, false>{});
            __syncthreads();
            buf ^= 1;
        }

        // ---- normalize + store: lane q = qw0 + l31; d = 32dg + 8m + 4hi + j
        const float l_tot = l_run + __shfl_xor(l_run, 32);
        const float linv  = 1.0f / l_tot;
        ushort* Op = Ob + ((size_t)b * SEQ + qw0 + l31) * D_MODEL + h * D_KK;
#pragma unroll
        for (int dg = 0; dg < 2; ++dg) {
            const f32x16& ot = dg ? ot1 : ot0;
#pragma unroll
            for (int m = 0; m < 4; ++m) {
                ushort4 u;
                u.x = f2bf(ot[4 * m + 0] * linv);
                u.y = f2bf(ot[4 * m + 1] * linv);
                u.z = f2bf(ot[4 * m + 2] * linv);
                u.w = f2bf(ot[4 * m + 3] * linv);
                *reinterpret_cast<ushort4*>(&Op[dg * 32 + m * 8 + 4 * hi]) = u;
            }
        }
        // loop's final __syncthreads already ran; LDS free to re-stage
    }
}

// ---------------------------------------------------------------------------
extern "C" void kernel_launch(void* const* d_in, const int* in_sizes, int n_in,
                              void* d_out, int out_size, void* d_ws, size_t ws_size,
                              hipStream_t stream)
{
    const float* x  = (const float*)d_in[0];
    const float* Wq = (const float*)d_in[2];
    const float* bq = (const float*)d_in[3];
    const float* Wk = (const float*)d_in[4];
    const float* bk = (const float*)d_in[5];
    const float* Wv = (const float*)d_in[6];
    const float* bv = (const float*)d_in[7];
    const float* Wo = (const float*)d_in[8];
    const float* bo = (const float*)d_in[9];
    float* out = (float*)d_out;

    const size_t TSZ = (size_t)M_TOTAL * D_MODEL;
    const size_t WSZ = (size_t)D_MODEL * D_MODEL;
    ushort* xb  = (ushort*)d_ws;
    ushort* Wqb = xb  + TSZ;
    ushort* Wkb = Wqb + WSZ;
    ushort* Wvb = Wkb + WSZ;
    ushort* Wob = Wvb + WSZ;
    ushort* Qb  = Wob + WSZ;
    ushort* Kb  = Qb  + TSZ;
    ushort* Vt  = Kb  + TSZ;
    ushort* Ob  = Vt  + TSZ;

    dim3 blk(256);
    cvt_kernel<<<dim3(256, 5), blk, 0, stream>>>(x, Wq, Wk, Wv, Wo,
                                                 xb, Wqb, Wkb, Wvb, Wob);

    // QKV: 32 mt x 16 nt x 3 z = 1536 blocks (flat, XCD-chunked decode)
    gemm_mfma<1><<<dim3(1536), blk, 0, stream>>>(xb, Wqb, bq, Qb,
                                                     Wkb, bk, Kb,
                                                     Wvb, bv, Vt);

    attn_mfma_kernel<<<dim3(512), dim3(128), 0, stream>>>(Qb, Kb, Vt, Ob);

    // O-proj: 32 mt x 16 nt = 512 blocks
    gemm_mfma<0><<<dim3(512), blk, 0, stream>>>(Ob, Wob, bo, out,
                                                    Wob, bo, out,
                                                    Wob, bo, out);
}

// Round 11
// 107.177 us; speedup vs baseline: 1.1267x; 1.1267x over previous
//
#include <hip/hip_runtime.h>
#include <math.h>
#include <type_traits>

#define D_MODEL 1024
#define N_HEADS 16
#define D_KK    64
#define B_SZ    2
#define SEQ     2048
#define M_TOTAL (B_SZ * SEQ)   // 4096

// 0.125 * log2(e): folds attention scale AND exp->exp2 conversion into Q
#define QSCALE 0.18033688011112042f
// fixed softmax "max" in exp2 domain (verified v6: |S| <~ 8; softmax is
// shift-invariant, bf16 P exponent-invariant -> no max-reduce needed)
#define FIXM 12.0f

typedef __attribute__((ext_vector_type(8)))  short short8;
typedef __attribute__((ext_vector_type(4)))  float f32x4;
typedef __attribute__((ext_vector_type(16))) float f32x16;

static __device__ __forceinline__ ushort f2bf(float f) {
    union { float f; unsigned u; } c; c.f = f;
    unsigned u = c.u;
    unsigned r = (u + 0x7fffu + ((u >> 16) & 1u)) >> 16;   // RNE
    return (ushort)r;
}

// v_cvt_pk_bf16_f32: dst = [bf16(b) : bf16(a)]
static __device__ __forceinline__ unsigned cvtpk(float a, float b) {
    unsigned r;
    asm("v_cvt_pk_bf16_f32 %0, %1, %2" : "=v"(r) : "v"(a), "v"(b));
    return r;
}
// v_permlane32_swap_b32: a.hi32lanes <-> b.lo32lanes
static __device__ __forceinline__ void pswap(unsigned &a, unsigned &b) {
    asm("v_permlane32_swap_b32 %0, %1" : "+v"(a), "+v"(b));
}

static __device__ __forceinline__ void gload16(const void* g, void* l) {
    __builtin_amdgcn_global_load_lds(
        (const __attribute__((address_space(1))) void*)g,
        (__attribute__((address_space(3))) void*)l, 16, 0, 0);
}

// ---------------------------------------------------------------------------
// fp32 -> bf16 conversion: x and the four weight matrices.
// ---------------------------------------------------------------------------
__global__ __launch_bounds__(256)
void cvt_kernel(const float* __restrict__ x,  const float* __restrict__ wq,
                const float* __restrict__ wk, const float* __restrict__ wv,
                const float* __restrict__ wo,
                ushort* __restrict__ xb,  ushort* __restrict__ wqb,
                ushort* __restrict__ wkb, ushort* __restrict__ wvb,
                ushort* __restrict__ wob)
{
    const float* s; ushort* d; int n4;
    switch (blockIdx.y) {
        case 0:  s = x;  d = xb;  n4 = M_TOTAL * D_MODEL / 4; break;
        case 1:  s = wq; d = wqb; n4 = D_MODEL * D_MODEL / 4; break;
        case 2:  s = wk; d = wkb; n4 = D_MODEL * D_MODEL / 4; break;
        case 3:  s = wv; d = wvb; n4 = D_MODEL * D_MODEL / 4; break;
        default: s = wo; d = wob; n4 = D_MODEL * D_MODEL / 4; break;
    }
    const int stride = gridDim.x * blockDim.x;
    for (int i = blockIdx.x * blockDim.x + threadIdx.x; i < n4; i += stride) {
        float4 v = reinterpret_cast<const float4*>(s)[i];
        ushort4 u;
        u.x = f2bf(v.x); u.y = f2bf(v.y); u.z = f2bf(v.z); u.w = f2bf(v.w);
        reinterpret_cast<ushort4*>(d)[i] = u;
    }
}

// ---------------------------------------------------------------------------
// bf16 MFMA GEMM v2 (unchanged): BM=128 BN=64 BK=64, dbuf prefetch,
// pre-swizzled global_load_lds, XCD-chunked flat decode.
// ---------------------------------------------------------------------------
template<int EPI>
__global__ __launch_bounds__(256)
void gemm_mfma(const ushort* __restrict__ A,
               const ushort* __restrict__ W0, const float* __restrict__ b0, void* __restrict__ C0,
               const ushort* __restrict__ W1, const float* __restrict__ b1, void* __restrict__ C1,
               const ushort* __restrict__ W2, const float* __restrict__ b2, void* __restrict__ C2)
{
    constexpr int K = D_MODEL;

    __shared__ ushort As[2][128 * 64];   // 32 KB
    __shared__ ushort Bs[2][64 * 64];    // 16 KB

    const int id  = blockIdx.x;
    const int xcd = id & 7;
    const int j   = id >> 3;
    const int mt  = xcd * 4 + (j & 3);
    const int ntz = j >> 2;
    const int nt  = ntz & 15;
    const int z   = ntz >> 4;

    const ushort* W    = W0;
    const float*  bias = b0;
    void*         C    = C0;
    if (z == 1) { W = W1; bias = b1; C = C1; }
    else if (z == 2) { W = W2; bias = b2; C = C2; }

    const int m0 = mt * 128;
    const int n0 = nt * 64;

    const int tid  = threadIdx.x;
    const int w    = tid >> 6;
    const int lane = tid & 63;
    const int lr   = lane & 15;
    const int lc   = lane >> 4;
    const int wr   = w >> 1;
    const int wc   = w & 1;

    const int rsub = lane >> 3;
    const int csw  = ((lane & 7) ^ rsub) << 3;

    const ushort* gA = A + (size_t)(m0 + w * 8 + rsub) * K + csw;
    const ushort* gB = W + (size_t)(n0 + w * 8 + rsub) * K + csw;

    f32x4 acc[4][2];
#pragma unroll
    for (int m = 0; m < 4; ++m)
#pragma unroll
        for (int n = 0; n < 2; ++n) acc[m][n] = (f32x4)0.0f;

#pragma unroll
    for (int ca = 0; ca < 4; ++ca)
        gload16(gA + (size_t)(32 * ca) * K, &As[0][(w + 4 * ca) * 512]);
#pragma unroll
    for (int cb = 0; cb < 2; ++cb)
        gload16(gB + (size_t)(32 * cb) * K, &Bs[0][(w + 4 * cb) * 512]);
    __syncthreads();

    const int swz = (lr & 7) << 4;
    int buf = 0;
    for (int it = 0; it < 16; ++it) {
        if (it < 15) {
            const int kn = (it + 1) * 64;
#pragma unroll
            for (int ca = 0; ca < 4; ++ca)
                gload16(gA + (size_t)(32 * ca) * K + kn, &As[buf ^ 1][(w + 4 * ca) * 512]);
#pragma unroll
            for (int cb = 0; cb < 2; ++cb)
                gload16(gB + (size_t)(32 * cb) * K + kn, &Bs[buf ^ 1][(w + 4 * cb) * 512]);
        }

        short8 af[4][2], bfr[2][2];
#pragma unroll
        for (int m = 0; m < 4; ++m) {
            const int rbyte = (wr * 64 + m * 16 + lr) * 128;
#pragma unroll
            for (int kk = 0; kk < 2; ++kk)
                af[m][kk] = *reinterpret_cast<const short8*>(
                    &As[buf][(rbyte + ((kk * 64 + lc * 16) ^ swz)) >> 1]);
        }
#pragma unroll
        for (int n = 0; n < 2; ++n) {
            const int rbyte = (wc * 32 + n * 16 + lr) * 128;
#pragma unroll
            for (int kk = 0; kk < 2; ++kk)
                bfr[n][kk] = *reinterpret_cast<const short8*>(
                    &Bs[buf][(rbyte + ((kk * 64 + lc * 16) ^ swz)) >> 1]);
        }
#pragma unroll
        for (int kk = 0; kk < 2; ++kk)
#pragma unroll
            for (int m = 0; m < 4; ++m)
#pragma unroll
                for (int n = 0; n < 2; ++n)
                    acc[m][n] = __builtin_amdgcn_mfma_f32_16x16x32_bf16(
                        af[m][kk], bfr[n][kk], acc[m][n], 0, 0, 0);

        __syncthreads();
        buf ^= 1;
    }

    float bv[2];
#pragma unroll
    for (int n = 0; n < 2; ++n) bv[n] = bias[n0 + wc * 32 + n * 16 + lr];
    const int row_base = m0 + wr * 64;

    if (EPI == 0) {
        float* Cf = (float*)C;
#pragma unroll
        for (int m = 0; m < 4; ++m)
#pragma unroll
        for (int r = 0; r < 4; ++r) {
            const int row = row_base + m * 16 + lc * 4 + r;
#pragma unroll
            for (int n = 0; n < 2; ++n)
                Cf[(size_t)row * D_MODEL + n0 + wc * 32 + n * 16 + lr] =
                    acc[m][n][r] + bv[n];
        }
    } else {
        ushort* Cu = (ushort*)C;
        const bool vt   = (z == 2);
        const float osc = (z == 0) ? QSCALE : 1.0f;
#pragma unroll
        for (int m = 0; m < 4; ++m) {
            const int row4 = row_base + m * 16 + lc * 4;
            const int bb = row4 >> 11;
            const int ss = row4 & 2047;
            const size_t bhbase = (size_t)bb * N_HEADS;
#pragma unroll
            for (int n = 0; n < 2; ++n) {
                const int col = n0 + wc * 32 + n * 16 + lr;
                const int h = col >> 6, d = col & 63;
                if (vt) {
                    ushort4 u;
                    u.x = f2bf(acc[m][n][0] + bv[n]);
                    u.y = f2bf(acc[m][n][1] + bv[n]);
                    u.z = f2bf(acc[m][n][2] + bv[n]);
                    u.w = f2bf(acc[m][n][3] + bv[n]);
                    *reinterpret_cast<ushort4*>(
                        &Cu[((bhbase + h) * D_KK + d) * SEQ + ss]) = u;
                } else {
#pragma unroll
                    for (int r = 0; r < 4; ++r)
                        Cu[((bhbase + h) * SEQ + ss + r) * D_KK + d] =
                            f2bf((acc[m][n][r] + bv[n]) * osc);
                }
            }
        }
    }
}

// ---------------------------------------------------------------------------
// MFMA flash attention v8: v6's verified per-wave math (32x32x16, in-register
// P via cvt_pk+permlane32_swap, fixed-max exp2 softmax), 4 waves/block by
// q-parallelism: waves {0,1} = 32-q halves of qb_a=qx; waves {2,3} = halves of
// qb_b=31-qx. All share one staged K/V tile stream (k-ranges nest); waves skip
// bodies past their diagonal (wave-uniform branch, no barrier inside).
// No cross-wave combine. 512 blocks, ~uniform work, 8 waves/CU.
// ---------------------------------------------------------------------------
__global__ __launch_bounds__(256, 2)
void attn_mfma_kernel(const ushort* __restrict__ Qb, const ushort* __restrict__ Kb,
                      const ushort* __restrict__ Vt, ushort* __restrict__ Ob)
{
    __shared__ ushort Ks[2][4096];      // [64 k][128 B], XOR-swizzled rows
    __shared__ ushort Vs[2][4096];      // [64 d][128 B] (V^T), XOR-swizzled

    const int tid  = threadIdx.x;
    const int w    = tid >> 6;           // 0..3
    const int lane = tid & 63;
    const int l31  = lane & 31;
    const int hi   = lane >> 5;
    const int swl  = (lane & 7) << 4;    // frag-read XOR (bytes)

    // 512 = 8 xcd * 4 bh * 16 q-pairs
    const int id  = blockIdx.x;
    const int xcd = id & 7;
    const int j   = id >> 3;             // 0..63
    const int bh  = xcd * 4 + (j & 3);
    const int qx  = j >> 2;              // 0..15
    const int b   = bh >> 4;
    const int h   = bh & 15;

    // wave's own q-block: waves 0,1 -> qx; waves 2,3 -> 31-qx
    const int myqb = (w < 2) ? qx : (31 - qx);
    const int qw0  = myqb * 64 + (w & 1) * 32;    // first q row of this wave
    const int qr   = (w & 1) * 32 + l31;          // q offset within 64-block
    const int ntmx = 32 - qx;                     // tiles staged (>= myqb+1)

    const ushort* Kbase = Kb + (size_t)bh * SEQ * D_KK;
    const ushort* Vbase = Vt + (size_t)bh * D_KK * SEQ;

    // staging: 8 chunks of 1KB per matrix; wave w does chunks {w, w+4};
    // source col pre-swizzled -> linear LDS dest lands XOR-swizzled
    const int rsub = lane >> 3;
    const int csw  = ((lane & 7) ^ rsub) << 3;

    auto stage = [&](int kofs, int s) {
#pragma unroll
        for (int cc = 0; cc < 2; ++cc) {
            const int c = w + cc * 4;
            gload16(Kbase + (size_t)(kofs + c * 8 + rsub) * D_KK + csw,
                    &Ks[s][c * 512]);
            gload16(Vbase + (size_t)(c * 8 + rsub) * SEQ + kofs + csw,
                    &Vs[s][c * 512]);
        }
    };

    // build PV B-frag from 8 packed f32 p-values (verified v6)
    auto makefrag = [&](const f32x16& sv, int o) -> short8 {
        unsigned u0 = cvtpk(sv[o + 0], sv[o + 1]);
        unsigned u1 = cvtpk(sv[o + 2], sv[o + 3]);
        unsigned u2 = cvtpk(sv[o + 4], sv[o + 5]);
        unsigned u3 = cvtpk(sv[o + 6], sv[o + 7]);
        pswap(u0, u2);
        pswap(u1, u3);
        int4 t = make_int4((int)u0, (int)u1, (int)u2, (int)u3);
        return *reinterpret_cast<short8*>(&t);
    };

    // Q B-frags: col q = l31, d = 16*ds + 8*hi + j (held whole kernel)
    const ushort* Qp = Qb + ((size_t)bh * SEQ + qw0 + l31) * D_KK + 8 * hi;
    short8 qf[4];
#pragma unroll
    for (int ds = 0; ds < 4; ++ds)
        qf[ds] = *reinterpret_cast<const short8*>(Qp + 16 * ds);

    f32x16 ot0 = (f32x16)0.0f, ot1 = (f32x16)0.0f;
    float l_run = 0.0f;

    stage(0, 0);
    __syncthreads();

    int buf = 0;
    for (int it = 0; it < ntmx; ++it) {
        if (it + 1 < ntmx) stage((it + 1) * 64, buf ^ 1);

        if (it <= myqb) {                       // wave-uniform participation
            const ushort* Ksb = &Ks[buf][0];
            const ushort* Vsb = &Vs[buf][0];

            // ---- S^T (64k x 32q) = K . Q^T : 8 MFMA, 8 K-reads ----
            f32x16 s0 = (f32x16)0.0f, s1 = (f32x16)0.0f;
#pragma unroll
            for (int ds = 0; ds < 4; ++ds) {
                const int cb = (32 * ds + 16 * hi) ^ swl;
                const short8 a0 = *reinterpret_cast<const short8*>(
                    &Ksb[(l31 * 128 + cb) >> 1]);
                const short8 a1 = *reinterpret_cast<const short8*>(
                    &Ksb[((32 + l31) * 128 + cb) >> 1]);
                s0 = __builtin_amdgcn_mfma_f32_32x32x16_bf16(a0, qf[ds], s0, 0, 0, 0);
                s1 = __builtin_amdgcn_mfma_f32_32x32x16_bf16(a1, qf[ds], s1, 0, 0, 0);
            }

            // ---- causal mask (diagonal tile only; wave-uniform test) ----
            if (it == myqb) {
#pragma unroll
                for (int reg = 0; reg < 16; ++reg) {
                    const int k32 = (reg & 3) + 8 * (reg >> 2) + 4 * hi;
                    if (k32 > qr)      s0[reg] = -1e30f;
                    if (k32 + 32 > qr) s1[reg] = -1e30f;
                }
            }

            // ---- p = exp2(s - FIXM); lane-local row sum ----
            float rsum = 0.0f;
#pragma unroll
            for (int reg = 0; reg < 16; ++reg) {
                const float p0 = __builtin_amdgcn_exp2f(s0[reg] - FIXM);
                const float p1 = __builtin_amdgcn_exp2f(s1[reg] - FIXM);
                s0[reg] = p0; s1[reg] = p1;
                rsum += p0 + p1;
            }
            l_run += rsum;

            // ---- P -> B-frags in-register ----
            const short8 pb0 = makefrag(s0, 0);
            const short8 pb1 = makefrag(s0, 8);
            const short8 pb2 = makefrag(s1, 0);
            const short8 pb3 = makefrag(s1, 8);

            // ---- O^T (64d x 32q) += V^T . P^T : 8 MFMA, 8 V-reads ----
#pragma unroll
            for (int dg = 0; dg < 2; ++dg) {
                const int row = dg * 32 + l31;
                f32x16& ot = dg ? ot1 : ot0;
#pragma unroll
                for (int ks = 0; ks < 4; ++ks) {
                    const int cb = (32 * ks + 16 * hi) ^ swl;
                    const short8 vf = *reinterpret_cast<const short8*>(
                        &Vsb[(row * 128 + cb) >> 1]);
                    const short8 pb = (ks == 0) ? pb0 : (ks == 1) ? pb1
                                     : (ks == 2) ? pb2 : pb3;
                    ot = __builtin_amdgcn_mfma_f32_32x32x16_bf16(vf, pb, ot, 0, 0, 0);
                }
            }
        }

        __syncthreads();
        buf ^= 1;
    }

    // ---- normalize + store (per wave; verified v6) ----
    const float l_tot = l_run + __shfl_xor(l_run, 32);
    const float linv  = 1.0f / l_tot;
    ushort* Op = Ob + ((size_t)b * SEQ + qw0 + l31) * D_MODEL + h * D_KK;
#pragma unroll
    for (int dg = 0; dg < 2; ++dg) {
        const f32x16& ot = dg ? ot1 : ot0;
#pragma unroll
        for (int m = 0; m < 4; ++m) {
            ushort4 u;
            u.x = f2bf(ot[4 * m + 0] * linv);
            u.y = f2bf(ot[4 * m + 1] * linv);
            u.z = f2bf(ot[4 * m + 2] * linv);
            u.w = f2bf(ot[4 * m + 3] * linv);
            *reinterpret_cast<ushort4*>(&Op[dg * 32 + m * 8 + 4 * hi]) = u;
        }
    }
}

// ---------------------------------------------------------------------------
extern "C" void kernel_launch(void* const* d_in, const int* in_sizes, int n_in,
                              void* d_out, int out_size, void* d_ws, size_t ws_size,
                              hipStream_t stream)
{
    const float* x  = (const float*)d_in[0];
    const float* Wq = (const float*)d_in[2];
    const float* bq = (const float*)d_in[3];
    const float* Wk = (const float*)d_in[4];
    const float* bk = (const float*)d_in[5];
    const float* Wv = (const float*)d_in[6];
    const float* bv = (const float*)d_in[7];
    const float* Wo = (const float*)d_in[8];
    const float* bo = (const float*)d_in[9];
    float* out = (float*)d_out;

    const size_t TSZ = (size_t)M_TOTAL * D_MODEL;
    const size_t WSZ = (size_t)D_MODEL * D_MODEL;
    ushort* xb  = (ushort*)d_ws;
    ushort* Wqb = xb  + TSZ;
    ushort* Wkb = Wqb + WSZ;
    ushort* Wvb = Wkb + WSZ;
    ushort* Wob = Wvb + WSZ;
    ushort* Qb  = Wob + WSZ;
    ushort* Kb  = Qb  + TSZ;
    ushort* Vt  = Kb  + TSZ;
    ushort* Ob  = Vt  + TSZ;

    dim3 blk(256);
    cvt_kernel<<<dim3(256, 5), blk, 0, stream>>>(x, Wq, Wk, Wv, Wo,
                                                 xb, Wqb, Wkb, Wvb, Wob);

    // QKV: 32 mt x 16 nt x 3 z = 1536 blocks (flat, XCD-chunked decode)
    gemm_mfma<1><<<dim3(1536), blk, 0, stream>>>(xb, Wqb, bq, Qb,
                                                     Wkb, bk, Kb,
                                                     Wvb, bv, Vt);

    attn_mfma_kernel<<<dim3(512), blk, 0, stream>>>(Qb, Kb, Vt, Ob);

    // O-proj: 32 mt x 16 nt = 512 blocks
    gemm_mfma<0><<<dim3(512), blk, 0, stream>>>(Ob, Wob, bo, out,
                                                    Wob, bo, out,
                                                    Wob, bo, out);
}